// Round 3
// baseline (231.479 us; speedup 1.0000x reference)
//
#include <hip/hip_runtime.h>

// MHSA: B=2, T=2048, C=1024, H=16, hd=64.
// Device dtypes: inputs f32 (verified: npz size + round-1 NaN), output f32
// (verified: round-2 error signature == packed-bf16-read-as-f32).
// Pipeline: cvt(x,Wqkv,Wproj -> bf16 ws) -> QKV GEMM (scatter Q*0.125,K,V^T)
// -> flash attn -> proj GEMM (f32 out). Intermediates bf16 in ws.

typedef __bf16 bf16x4 __attribute__((ext_vector_type(4)));
typedef __bf16 bf16x8 __attribute__((ext_vector_type(8)));
typedef float  f32x4  __attribute__((ext_vector_type(4)));

#define AS1(p) ((const __attribute__((address_space(1))) void*)(p))
#define AS3(p) ((__attribute__((address_space(3))) void*)(p))

// ---------------------------------------------------------------------------
// f32 -> bf16 elementwise convert (vectorized, grid-stride). n % 4 == 0.
// ---------------------------------------------------------------------------
__global__ __launch_bounds__(256)
void cvt_f32_bf16(const float* __restrict__ in, __bf16* __restrict__ out, int n)
{
    const int stride = gridDim.x * blockDim.x * 4;
    for (int i = (blockIdx.x * blockDim.x + threadIdx.x) * 4; i < n; i += stride) {
        const float4 v = *(const float4*)(in + i);
        bf16x4 o = { (__bf16)v.x, (__bf16)v.y, (__bf16)v.z, (__bf16)v.w };
        *(bf16x4*)(out + i) = o;
    }
}

// ---------------------------------------------------------------------------
// GEMM: out[m][n] = sum_k A[m][k] * W[n][k] + bias[n]   (NT layout, bf16 in,
// f32 bias). 128x128 tile, BK=64, 256 threads (4 waves 2x2), 16x16x32 MFMA.
// MODE 0: QKV epilogue (scatter into Qs*0.125/Ks/Vt, bf16).
// MODE 1: plain f32 out (final projection -> d_out).
// ---------------------------------------------------------------------------
template<int MODE>
__global__ __launch_bounds__(256)
void gemm_bt(const __bf16* __restrict__ A, const __bf16* __restrict__ W,
             const float* __restrict__ bias, int M, int N, int K,
             __bf16* __restrict__ O0, __bf16* __restrict__ O1,
             __bf16* __restrict__ O2, float* __restrict__ Of)
{
    __shared__ __bf16 sA[128 * 64];
    __shared__ __bf16 sB[128 * 64];
    const int tid  = threadIdx.x;
    const int w    = tid >> 6, lane = tid & 63;
    const int g    = lane >> 4, r16 = lane & 15;
    const int tM   = blockIdx.y * 128, tN = blockIdx.x * 128;
    const int wr   = w >> 1, wc = w & 1;
    const int crow = lane >> 3;        // row within 8-row chunk
    const int ccol = (lane & 7) * 8;   // element col within BK

    f32x4 acc[4][4] = {};

    for (int k0 = 0; k0 < K; k0 += 64) {
        // ---- stage A-tile and B-tile via async global->LDS (16B/lane) ----
#pragma unroll
        for (int c = w; c < 16; c += 4) {
            const __bf16* ga = A + (size_t)(tM + c * 8 + crow) * K + k0 + ccol;
            __builtin_amdgcn_global_load_lds(AS1(ga), AS3(&sA[c * 8 * 64]), 16, 0, 0);
            const __bf16* gb = W + (size_t)(tN + c * 8 + crow) * K + k0 + ccol;
            __builtin_amdgcn_global_load_lds(AS1(gb), AS3(&sB[c * 8 * 64]), 16, 0, 0);
        }
        __syncthreads();
        // ---- compute: 2 K-steps of 32, 4x4 fragments per wave ----
#pragma unroll
        for (int kk = 0; kk < 2; ++kk) {
            bf16x8 a[4], b[4];
#pragma unroll
            for (int mf = 0; mf < 4; ++mf)
                a[mf] = *(const bf16x8*)&sA[(wr * 64 + mf * 16 + r16) * 64 + kk * 32 + g * 8];
#pragma unroll
            for (int nf = 0; nf < 4; ++nf)
                b[nf] = *(const bf16x8*)&sB[(wc * 64 + nf * 16 + r16) * 64 + kk * 32 + g * 8];
#pragma unroll
            for (int mf = 0; mf < 4; ++mf)
#pragma unroll
                for (int nf = 0; nf < 4; ++nf)
                    acc[mf][nf] = __builtin_amdgcn_mfma_f32_16x16x32_bf16(
                        a[mf], b[nf], acc[mf][nf], 0, 0, 0);
        }
        __syncthreads();
    }

    // ---- epilogue: C/D layout col = lane&15, row = (lane>>4)*4 + reg ----
#pragma unroll
    for (int mf = 0; mf < 4; ++mf) {
#pragma unroll
        for (int nf = 0; nf < 4; ++nf) {
#pragma unroll
            for (int reg = 0; reg < 4; ++reg) {
                const int row = tM + wr * 64 + mf * 16 + g * 4 + reg;
                const int col = tN + wc * 64 + nf * 16 + r16;
                float v = acc[mf][nf][reg] + bias[col];
                if (MODE == 0) {
                    // col -> (h, j) per reshape (H, 3*hd): h = col/192, j = col%192
                    const int h = col / 192, j = col % 192;
                    const int b = row >> 11, t = row & 2047;
                    const size_t bh = (size_t)(b * 16 + h);
                    if (j < 64)
                        O0[(bh * 2048 + t) * 64 + j] = (__bf16)(v * 0.125f);
                    else if (j < 128)
                        O1[(bh * 2048 + t) * 64 + (j - 64)] = (__bf16)v;
                    else
                        O2[(bh * 64 + (j - 128)) * 2048 + t] = (__bf16)v;
                } else {
                    Of[(size_t)row * N + col] = v;
                }
            }
        }
    }
}

// ---------------------------------------------------------------------------
// Flash attention (non-causal). Grid (16 qblocks, 16 heads, 2 batch), 256 thr.
// Each wave: 32 q-rows, iterates 32 KV tiles of 64 keys. K and Vt read from
// global (256 KB/head -> L2-resident). P converted C/D->A layout via LDS.
// ---------------------------------------------------------------------------
__global__ __launch_bounds__(256)
void attn(const __bf16* __restrict__ Q, const __bf16* __restrict__ K,
          const __bf16* __restrict__ V, __bf16* __restrict__ O)
{
    __shared__ __bf16 P[4][32][72];   // per-wave, stride 72 (2-way bank alias = free)
    const int tid = threadIdx.x;
    const int w   = tid >> 6, lane = tid & 63;
    const int g   = lane >> 4, r16 = lane & 15;
    const int bh  = blockIdx.z * 16 + blockIdx.y;
    const int q0  = blockIdx.x * 128 + w * 32;
    const __bf16* Qp = Q + (size_t)bh * 2048 * 64;
    const __bf16* Kp = K + (size_t)bh * 2048 * 64;
    const __bf16* Vp = V + (size_t)bh * 64 * 2048;

    // Q fragments (A-operand): m = lane&15, k = (lane>>4)*8..+7
    bf16x8 qa[2][2];
#pragma unroll
    for (int mf = 0; mf < 2; ++mf)
#pragma unroll
        for (int kk = 0; kk < 2; ++kk)
            qa[mf][kk] = *(const bf16x8*)(Qp + (size_t)(q0 + mf * 16 + r16) * 64 + kk * 32 + g * 8);

    f32x4 o[2][4] = {};
    float mrun[2][4], lrun[2][4];
#pragma unroll
    for (int mf = 0; mf < 2; ++mf)
#pragma unroll
        for (int r = 0; r < 4; ++r) { mrun[mf][r] = -1e30f; lrun[mf][r] = 0.f; }

    for (int kv = 0; kv < 2048; kv += 64) {
        // ---- S = Q K^T (scale pre-applied to Q) ----
        bf16x8 kb[4][2];
#pragma unroll
        for (int nf = 0; nf < 4; ++nf)
#pragma unroll
            for (int kk = 0; kk < 2; ++kk)
                kb[nf][kk] = *(const bf16x8*)(Kp + (size_t)(kv + nf * 16 + r16) * 64 + kk * 32 + g * 8);
        f32x4 S[2][4];
#pragma unroll
        for (int mf = 0; mf < 2; ++mf)
#pragma unroll
            for (int nf = 0; nf < 4; ++nf) {
                f32x4 s = {};
                s = __builtin_amdgcn_mfma_f32_16x16x32_bf16(qa[mf][0], kb[nf][0], s, 0, 0, 0);
                s = __builtin_amdgcn_mfma_f32_16x16x32_bf16(qa[mf][1], kb[nf][1], s, 0, 0, 0);
                S[mf][nf] = s;
            }
        // ---- online softmax (row = mf*16+g*4+reg; 16 lanes of group g share) ----
#pragma unroll
        for (int mf = 0; mf < 2; ++mf) {
#pragma unroll
            for (int reg = 0; reg < 4; ++reg) {
                float rm = fmaxf(fmaxf(S[mf][0][reg], S[mf][1][reg]),
                                 fmaxf(S[mf][2][reg], S[mf][3][reg]));
                rm = fmaxf(rm, __shfl_xor(rm, 1));
                rm = fmaxf(rm, __shfl_xor(rm, 2));
                rm = fmaxf(rm, __shfl_xor(rm, 4));
                rm = fmaxf(rm, __shfl_xor(rm, 8));
                const float mo = mrun[mf][reg];
                const float mn = fmaxf(mo, rm);
                const float al = __expf(mo - mn);
                float rs = 0.f;
#pragma unroll
                for (int nf = 0; nf < 4; ++nf) {
                    float p = __expf(S[mf][nf][reg] - mn);
                    S[mf][nf][reg] = p;
                    rs += p;
                }
                rs += __shfl_xor(rs, 1);
                rs += __shfl_xor(rs, 2);
                rs += __shfl_xor(rs, 4);
                rs += __shfl_xor(rs, 8);
                lrun[mf][reg] = lrun[mf][reg] * al + rs;
                mrun[mf][reg] = mn;
#pragma unroll
                for (int df = 0; df < 4; ++df) o[mf][df][reg] *= al;
            }
        }
        // ---- P: C/D layout -> LDS -> A-fragment layout ----
        asm volatile("s_waitcnt lgkmcnt(0)" ::: "memory");  // WAR vs prev iter reads
#pragma unroll
        for (int mf = 0; mf < 2; ++mf)
#pragma unroll
            for (int nf = 0; nf < 4; ++nf)
#pragma unroll
                for (int reg = 0; reg < 4; ++reg)
                    P[w][mf * 16 + g * 4 + reg][nf * 16 + r16] = (__bf16)S[mf][nf][reg];
        asm volatile("s_waitcnt lgkmcnt(0)" ::: "memory");  // writes visible to own wave
        // ---- O += P V  (B-operand from Vt: n = d, k = key, contiguous) ----
#pragma unroll
        for (int kk = 0; kk < 2; ++kk) {
            bf16x8 pa[2];
#pragma unroll
            for (int mf = 0; mf < 2; ++mf)
                pa[mf] = *(const bf16x8*)&P[w][mf * 16 + r16][kk * 32 + g * 8];
#pragma unroll
            for (int df = 0; df < 4; ++df) {
                bf16x8 vb = *(const bf16x8*)(Vp + (size_t)(df * 16 + r16) * 2048 + kv + kk * 32 + g * 8);
#pragma unroll
                for (int mf = 0; mf < 2; ++mf)
                    o[mf][df] = __builtin_amdgcn_mfma_f32_16x16x32_bf16(pa[mf], vb, o[mf][df], 0, 0, 0);
            }
        }
    }
    // ---- normalize and store O as (B*T, C) ----
#pragma unroll
    for (int mf = 0; mf < 2; ++mf)
#pragma unroll
        for (int df = 0; df < 4; ++df)
#pragma unroll
            for (int reg = 0; reg < 4; ++reg) {
                const float v = o[mf][df][reg] / lrun[mf][reg];
                O[(size_t)(blockIdx.z * 2048 + q0 + mf * 16 + g * 4 + reg) * 1024
                  + blockIdx.y * 64 + df * 16 + r16] = (__bf16)v;
            }
}

// ---------------------------------------------------------------------------
extern "C" void kernel_launch(void* const* d_in, const int* in_sizes, int n_in,
                              void* d_out, int out_size, void* d_ws, size_t ws_size,
                              hipStream_t stream)
{
    const float* x     = (const float*)d_in[0];
    const float* Wqkv  = (const float*)d_in[1];
    const float* bqkv  = (const float*)d_in[2];
    const float* Wproj = (const float*)d_in[3];
    const float* bproj = (const float*)d_in[4];
    float* out = (float*)d_out;

    const size_t NX   = (size_t)4096 * 1024;   // x / per-tensor Q,K,V,O elements
    const size_t NWQ  = (size_t)3072 * 1024;
    const size_t NWP  = (size_t)1024 * 1024;

    __bf16* xb  = (__bf16*)d_ws;       // 4.19M
    __bf16* Wqb = xb  + NX;            // 3.15M
    __bf16* Wpb = Wqb + NWQ;           // 1.05M
    __bf16* Qs  = Wpb + NWP;           // 4.19M  (B,H,T,64), pre-scaled 0.125
    __bf16* Ks  = Qs  + NX;            // 4.19M  (B,H,T,64)
    __bf16* Vt  = Ks  + NX;            // 4.19M  (B,H,64,T)
    __bf16* Os  = Vt  + NX;            // 4.19M  (B*T, C)

    dim3 blk(256);
    cvt_f32_bf16<<<dim3(2048), blk, 0, stream>>>(x,     xb,  (int)NX);
    cvt_f32_bf16<<<dim3(2048), blk, 0, stream>>>(Wqkv,  Wqb, (int)NWQ);
    cvt_f32_bf16<<<dim3(1024), blk, 0, stream>>>(Wproj, Wpb, (int)NWP);

    gemm_bt<0><<<dim3(24, 32), blk, 0, stream>>>(xb, Wqb, bqkv, 4096, 3072, 1024, Qs, Ks, Vt, nullptr);
    attn<<<dim3(16, 16, 2), blk, 0, stream>>>(Qs, Ks, Vt, Os);
    gemm_bt<1><<<dim3(8, 32), blk, 0, stream>>>(Os, Wpb, bproj, 4096, 1024, 1024, nullptr, nullptr, nullptr, out);
}

// Round 4
// 186.300 us; speedup vs baseline: 1.2425x; 1.2425x over previous
//
#include <hip/hip_runtime.h>

// MHSA: B=2, T=2048, C=1024, H=16, hd=64. Inputs f32, output f32.
// cvt(x,Wqkv,Wproj->bf16) -> QKV GEMM (scatter Q*0.125,K,V^T) -> flash attn
// (block-staged K/V in LDS, double-buffered, XOR-swizzled) -> proj GEMM (f32).

typedef __bf16 bf16x4 __attribute__((ext_vector_type(4)));
typedef __bf16 bf16x8 __attribute__((ext_vector_type(8)));
typedef float  f32x4  __attribute__((ext_vector_type(4)));

#define AS1(p) ((const __attribute__((address_space(1))) void*)(p))
#define AS3(p) ((__attribute__((address_space(3))) void*)(p))

// ---------------------------------------------------------------------------
__global__ __launch_bounds__(256)
void cvt_f32_bf16(const float* __restrict__ in, __bf16* __restrict__ out, int n)
{
    const int stride = gridDim.x * blockDim.x * 4;
    for (int i = (blockIdx.x * blockDim.x + threadIdx.x) * 4; i < n; i += stride) {
        const float4 v = *(const float4*)(in + i);
        bf16x4 o = { (__bf16)v.x, (__bf16)v.y, (__bf16)v.z, (__bf16)v.w };
        *(bf16x4*)(out + i) = o;
    }
}

// ---------------------------------------------------------------------------
// GEMM out[m][n] = sum_k A[m][k]*W[n][k] + bias[n]. 128x128 tile, BK=64.
// MODE 0: QKV scatter epilogue (bf16).  MODE 1: f32 out (final projection).
// ---------------------------------------------------------------------------
template<int MODE>
__global__ __launch_bounds__(256)
void gemm_bt(const __bf16* __restrict__ A, const __bf16* __restrict__ W,
             const float* __restrict__ bias, int M, int N, int K,
             __bf16* __restrict__ O0, __bf16* __restrict__ O1,
             __bf16* __restrict__ O2, float* __restrict__ Of)
{
    __shared__ __bf16 sA[128 * 64];
    __shared__ __bf16 sB[128 * 64];
    const int tid  = threadIdx.x;
    const int w    = tid >> 6, lane = tid & 63;
    const int g    = lane >> 4, r16 = lane & 15;
    const int tM   = blockIdx.y * 128, tN = blockIdx.x * 128;
    const int wr   = w >> 1, wc = w & 1;
    const int crow = lane >> 3;
    const int ccol = (lane & 7) * 8;

    f32x4 acc[4][4] = {};

    for (int k0 = 0; k0 < K; k0 += 64) {
#pragma unroll
        for (int c = w; c < 16; c += 4) {
            const __bf16* ga = A + (size_t)(tM + c * 8 + crow) * K + k0 + ccol;
            __builtin_amdgcn_global_load_lds(AS1(ga), AS3(&sA[c * 8 * 64]), 16, 0, 0);
            const __bf16* gb = W + (size_t)(tN + c * 8 + crow) * K + k0 + ccol;
            __builtin_amdgcn_global_load_lds(AS1(gb), AS3(&sB[c * 8 * 64]), 16, 0, 0);
        }
        __syncthreads();
#pragma unroll
        for (int kk = 0; kk < 2; ++kk) {
            bf16x8 a[4], b[4];
#pragma unroll
            for (int mf = 0; mf < 4; ++mf)
                a[mf] = *(const bf16x8*)&sA[(wr * 64 + mf * 16 + r16) * 64 + kk * 32 + g * 8];
#pragma unroll
            for (int nf = 0; nf < 4; ++nf)
                b[nf] = *(const bf16x8*)&sB[(wc * 64 + nf * 16 + r16) * 64 + kk * 32 + g * 8];
#pragma unroll
            for (int mf = 0; mf < 4; ++mf)
#pragma unroll
                for (int nf = 0; nf < 4; ++nf)
                    acc[mf][nf] = __builtin_amdgcn_mfma_f32_16x16x32_bf16(
                        a[mf], b[nf], acc[mf][nf], 0, 0, 0);
        }
        __syncthreads();
    }

#pragma unroll
    for (int mf = 0; mf < 4; ++mf) {
#pragma unroll
        for (int nf = 0; nf < 4; ++nf) {
#pragma unroll
            for (int reg = 0; reg < 4; ++reg) {
                const int row = tM + wr * 64 + mf * 16 + g * 4 + reg;
                const int col = tN + wc * 64 + nf * 16 + r16;
                float v = acc[mf][nf][reg] + bias[col];
                if (MODE == 0) {
                    const int h = col / 192, j = col % 192;
                    const int b = row >> 11, t = row & 2047;
                    const size_t bh = (size_t)(b * 16 + h);
                    if (j < 64)
                        O0[(bh * 2048 + t) * 64 + j] = (__bf16)(v * 0.125f);
                    else if (j < 128)
                        O1[(bh * 2048 + t) * 64 + (j - 64)] = (__bf16)v;
                    else
                        O2[(bh * 64 + (j - 128)) * 2048 + t] = (__bf16)v;
                } else {
                    Of[(size_t)row * N + col] = v;
                }
            }
        }
    }
}

// ---------------------------------------------------------------------------
// Flash attention. Grid (16 qblocks, 16 heads, 2 batch), 256 thr (4 waves).
// Block stages K-tile [64kv][64d] and V^T-tile [64d][64kv] in LDS
// (double-buffered, XOR-swizzled byte^=((row&7)<<4)); all 4 waves share them.
// Per wave: 32 q-rows. Online softmax with per-lane partial denominators
// (cross-lane sum-reduce deferred to the epilogue).
// ---------------------------------------------------------------------------
__global__ __launch_bounds__(256)
void attn(const __bf16* __restrict__ Q, const __bf16* __restrict__ K,
          const __bf16* __restrict__ V, __bf16* __restrict__ O)
{
    __shared__ __bf16 sK[2][64 * 64];   // 8 KB each, swizzled
    __shared__ __bf16 sV[2][64 * 64];   // V^T tile [d][kv], swizzled
    __shared__ __bf16 P[4][32][72];     // per-wave P staging (stride 72)

    const int tid = threadIdx.x;
    const int w   = tid >> 6, lane = tid & 63;
    const int g   = lane >> 4, r16 = lane & 15;
    const int bh  = blockIdx.z * 16 + blockIdx.y;
    const int q0  = blockIdx.x * 128 + w * 32;
    const __bf16* Qp = Q + (size_t)bh * 2048 * 64;
    const __bf16* Kp = K + (size_t)bh * 2048 * 64;
    const __bf16* Vp = V + (size_t)bh * 64 * 2048;

    // staging geometry: per round r (0,1), wave w stages 1KB at lds byte
    // base = r*4096 + w*1024; lane's 16B goes to base + lane*16 (HW rule).
    const int srow_off = (lane >> 3);                    // row within 8-row chunk
    const int scol     = 8 * ((lane & 7) ^ (lane >> 3)); // pre-swizzled col (elems)

    // Q fragments (A-operand): m = r16, k = g*8 (+32 per kk)
    bf16x8 qa[2][2];
#pragma unroll
    for (int mf = 0; mf < 2; ++mf)
#pragma unroll
        for (int kk = 0; kk < 2; ++kk)
            qa[mf][kk] = *(const bf16x8*)(Qp + (size_t)(q0 + mf * 16 + r16) * 64 + kk * 32 + g * 8);

    f32x4 o[2][4] = {};
    float mrun[2][4], lrun[2][4];
#pragma unroll
    for (int mf = 0; mf < 2; ++mf)
#pragma unroll
        for (int r = 0; r < 4; ++r) { mrun[mf][r] = -1e30f; lrun[mf][r] = 0.f; }

    // ---- stage tile 0 ----
#pragma unroll
    for (int r = 0; r < 2; ++r) {
        const int ldsb = r * 4096 + w * 1024;
        const int row  = r * 32 + w * 8 + srow_off;
        __builtin_amdgcn_global_load_lds(AS1(Kp + (size_t)row * 64 + scol),
                                         AS3((char*)&sK[0][0] + ldsb), 16, 0, 0);
        __builtin_amdgcn_global_load_lds(AS1(Vp + (size_t)row * 2048 + scol),
                                         AS3((char*)&sV[0][0] + ldsb), 16, 0, 0);
    }
    __syncthreads();

    for (int t = 0; t < 32; ++t) {
        const int cur = t & 1;
        // ---- prefetch tile t+1 into the other buffer ----
        if (t < 31) {
            const int kvn = (t + 1) * 64;
#pragma unroll
            for (int r = 0; r < 2; ++r) {
                const int ldsb = r * 4096 + w * 1024;
                const int row  = r * 32 + w * 8 + srow_off;
                __builtin_amdgcn_global_load_lds(AS1(Kp + (size_t)(kvn + row) * 64 + scol),
                                                 AS3((char*)&sK[cur ^ 1][0] + ldsb), 16, 0, 0);
                __builtin_amdgcn_global_load_lds(AS1(Vp + (size_t)row * 2048 + kvn + scol),
                                                 AS3((char*)&sV[cur ^ 1][0] + ldsb), 16, 0, 0);
            }
        }
        // ---- S = Q K^T from LDS (swizzled reads, conflict-free) ----
        bf16x8 kb[4][2];
#pragma unroll
        for (int nf = 0; nf < 4; ++nf) {
            const int row = nf * 16 + r16;
#pragma unroll
            for (int kk = 0; kk < 2; ++kk) {
                const int cb = ((kk * 32 + g * 8) * 2) ^ ((row & 7) << 4);
                kb[nf][kk] = *(const bf16x8*)((const char*)&sK[cur][0] + row * 128 + cb);
            }
        }
        f32x4 S[2][4];
#pragma unroll
        for (int mf = 0; mf < 2; ++mf)
#pragma unroll
            for (int nf = 0; nf < 4; ++nf) {
                f32x4 s = {};
                s = __builtin_amdgcn_mfma_f32_16x16x32_bf16(qa[mf][0], kb[nf][0], s, 0, 0, 0);
                s = __builtin_amdgcn_mfma_f32_16x16x32_bf16(qa[mf][1], kb[nf][1], s, 0, 0, 0);
                S[mf][nf] = s;
            }
        // ---- online softmax: shfl only for row-max; denom is per-lane ----
#pragma unroll
        for (int mf = 0; mf < 2; ++mf) {
#pragma unroll
            for (int reg = 0; reg < 4; ++reg) {
                float rm = fmaxf(fmaxf(S[mf][0][reg], S[mf][1][reg]),
                                 fmaxf(S[mf][2][reg], S[mf][3][reg]));
                rm = fmaxf(rm, __shfl_xor(rm, 1));
                rm = fmaxf(rm, __shfl_xor(rm, 2));
                rm = fmaxf(rm, __shfl_xor(rm, 4));
                rm = fmaxf(rm, __shfl_xor(rm, 8));
                const float mo = mrun[mf][reg];
                const float mn = fmaxf(mo, rm);
                const float al = __expf(mo - mn);
                float rs = 0.f;
#pragma unroll
                for (int nf = 0; nf < 4; ++nf) {
                    float p = __expf(S[mf][nf][reg] - mn);
                    S[mf][nf][reg] = p;
                    rs += p;
                }
                lrun[mf][reg] = lrun[mf][reg] * al + rs;   // per-lane partial
                mrun[mf][reg] = mn;
#pragma unroll
                for (int df = 0; df < 4; ++df) o[mf][df][reg] *= al;
            }
        }
        // ---- P: C/D layout -> LDS -> A-fragment layout ----
        asm volatile("s_waitcnt lgkmcnt(0)" ::: "memory");
#pragma unroll
        for (int mf = 0; mf < 2; ++mf)
#pragma unroll
            for (int nf = 0; nf < 4; ++nf)
#pragma unroll
                for (int reg = 0; reg < 4; ++reg)
                    P[w][mf * 16 + g * 4 + reg][nf * 16 + r16] = (__bf16)S[mf][nf][reg];
        asm volatile("s_waitcnt lgkmcnt(0)" ::: "memory");
        // ---- O += P V from LDS ----
#pragma unroll
        for (int kk = 0; kk < 2; ++kk) {
            bf16x8 pa[2];
#pragma unroll
            for (int mf = 0; mf < 2; ++mf)
                pa[mf] = *(const bf16x8*)&P[w][mf * 16 + r16][kk * 32 + g * 8];
#pragma unroll
            for (int df = 0; df < 4; ++df) {
                const int row = df * 16 + r16;
                const int cb  = ((kk * 32 + g * 8) * 2) ^ ((row & 7) << 4);
                bf16x8 vb = *(const bf16x8*)((const char*)&sV[cur][0] + row * 128 + cb);
#pragma unroll
                for (int mf = 0; mf < 2; ++mf)
                    o[mf][df] = __builtin_amdgcn_mfma_f32_16x16x32_bf16(pa[mf], vb, o[mf][df], 0, 0, 0);
            }
        }
        __syncthreads();   // drains vmcnt (stage done) + all waves done with cur
    }

    // ---- finish denominator (one 16-lane reduce) and store ----
#pragma unroll
    for (int mf = 0; mf < 2; ++mf)
#pragma unroll
        for (int reg = 0; reg < 4; ++reg) {
            float l = lrun[mf][reg];
            l += __shfl_xor(l, 1);
            l += __shfl_xor(l, 2);
            l += __shfl_xor(l, 4);
            l += __shfl_xor(l, 8);
            lrun[mf][reg] = l;
        }
#pragma unroll
    for (int mf = 0; mf < 2; ++mf)
#pragma unroll
        for (int df = 0; df < 4; ++df)
#pragma unroll
            for (int reg = 0; reg < 4; ++reg) {
                const float v = o[mf][df][reg] / lrun[mf][reg];
                O[(size_t)(blockIdx.z * 2048 + q0 + mf * 16 + g * 4 + reg) * 1024
                  + blockIdx.y * 64 + df * 16 + r16] = (__bf16)v;
            }
}

// ---------------------------------------------------------------------------
extern "C" void kernel_launch(void* const* d_in, const int* in_sizes, int n_in,
                              void* d_out, int out_size, void* d_ws, size_t ws_size,
                              hipStream_t stream)
{
    const float* x     = (const float*)d_in[0];
    const float* Wqkv  = (const float*)d_in[1];
    const float* bqkv  = (const float*)d_in[2];
    const float* Wproj = (const float*)d_in[3];
    const float* bproj = (const float*)d_in[4];
    float* out = (float*)d_out;

    const size_t NX   = (size_t)4096 * 1024;
    const size_t NWQ  = (size_t)3072 * 1024;
    const size_t NWP  = (size_t)1024 * 1024;

    __bf16* xb  = (__bf16*)d_ws;
    __bf16* Wqb = xb  + NX;
    __bf16* Wpb = Wqb + NWQ;
    __bf16* Qs  = Wpb + NWP;           // (B,H,T,64), pre-scaled 0.125
    __bf16* Ks  = Qs  + NX;            // (B,H,T,64)
    __bf16* Vt  = Ks  + NX;            // (B,H,64,T)
    __bf16* Os  = Vt  + NX;            // (B*T, C)

    dim3 blk(256);
    cvt_f32_bf16<<<dim3(2048), blk, 0, stream>>>(x,     xb,  (int)NX);
    cvt_f32_bf16<<<dim3(2048), blk, 0, stream>>>(Wqkv,  Wqb, (int)NWQ);
    cvt_f32_bf16<<<dim3(1024), blk, 0, stream>>>(Wproj, Wpb, (int)NWP);

    gemm_bt<0><<<dim3(24, 32), blk, 0, stream>>>(xb, Wqb, bqkv, 4096, 3072, 1024, Qs, Ks, Vt, nullptr);
    attn<<<dim3(16, 16, 2), blk, 0, stream>>>(Qs, Ks, Vt, Os);
    gemm_bt<1><<<dim3(8, 32), blk, 0, stream>>>(Os, Wpb, bproj, 4096, 1024, 1024, nullptr, nullptr, nullptr, out);
}

// Round 5
// 156.514 us; speedup vs baseline: 1.4790x; 1.1903x over previous
//
#include <hip/hip_runtime.h>

// MHSA: B=2, T=2048, C=1024, H=16, hd=64. Inputs f32, output f32.
// cvt(x,Wqkv,Wproj->bf16) -> QKV GEMM (scatter Q*0.125*log2e, K, V^T)
// -> flash attn (swapped QK^T: softmax lane-local, exp2 domain, transposed PV)
// -> proj GEMM (f32 out). Intermediates bf16 in ws.

typedef __bf16 bf16x4 __attribute__((ext_vector_type(4)));
typedef __bf16 bf16x8 __attribute__((ext_vector_type(8)));
typedef float  f32x4  __attribute__((ext_vector_type(4)));

#define AS1(p) ((const __attribute__((address_space(1))) void*)(p))
#define AS3(p) ((__attribute__((address_space(3))) void*)(p))

// ---------------------------------------------------------------------------
__global__ __launch_bounds__(256)
void cvt_f32_bf16(const float* __restrict__ in, __bf16* __restrict__ out, int n)
{
    const int stride = gridDim.x * blockDim.x * 4;
    for (int i = (blockIdx.x * blockDim.x + threadIdx.x) * 4; i < n; i += stride) {
        const float4 v = *(const float4*)(in + i);
        bf16x4 o = { (__bf16)v.x, (__bf16)v.y, (__bf16)v.z, (__bf16)v.w };
        *(bf16x4*)(out + i) = o;
    }
}

// ---------------------------------------------------------------------------
// GEMM out[m][n] = sum_k A[m][k]*W[n][k] + bias[n]. 128x128 tile, BK=64.
// MODE 0: QKV scatter epilogue (bf16, Q scaled to exp2 domain).
// MODE 1: f32 out (final projection).
// ---------------------------------------------------------------------------
template<int MODE>
__global__ __launch_bounds__(256)
void gemm_bt(const __bf16* __restrict__ A, const __bf16* __restrict__ W,
             const float* __restrict__ bias, int M, int N, int K,
             __bf16* __restrict__ O0, __bf16* __restrict__ O1,
             __bf16* __restrict__ O2, float* __restrict__ Of)
{
    __shared__ __bf16 sA[128 * 64];
    __shared__ __bf16 sB[128 * 64];
    const int tid  = threadIdx.x;
    const int w    = tid >> 6, lane = tid & 63;
    const int g    = lane >> 4, r16 = lane & 15;
    const int tM   = blockIdx.y * 128, tN = blockIdx.x * 128;
    const int wr   = w >> 1, wc = w & 1;
    const int crow = lane >> 3;
    const int ccol = (lane & 7) * 8;

    f32x4 acc[4][4] = {};

    for (int k0 = 0; k0 < K; k0 += 64) {
#pragma unroll
        for (int c = w; c < 16; c += 4) {
            const __bf16* ga = A + (size_t)(tM + c * 8 + crow) * K + k0 + ccol;
            __builtin_amdgcn_global_load_lds(AS1(ga), AS3(&sA[c * 8 * 64]), 16, 0, 0);
            const __bf16* gb = W + (size_t)(tN + c * 8 + crow) * K + k0 + ccol;
            __builtin_amdgcn_global_load_lds(AS1(gb), AS3(&sB[c * 8 * 64]), 16, 0, 0);
        }
        __syncthreads();
#pragma unroll
        for (int kk = 0; kk < 2; ++kk) {
            bf16x8 a[4], b[4];
#pragma unroll
            for (int mf = 0; mf < 4; ++mf)
                a[mf] = *(const bf16x8*)&sA[(wr * 64 + mf * 16 + r16) * 64 + kk * 32 + g * 8];
#pragma unroll
            for (int nf = 0; nf < 4; ++nf)
                b[nf] = *(const bf16x8*)&sB[(wc * 64 + nf * 16 + r16) * 64 + kk * 32 + g * 8];
#pragma unroll
            for (int mf = 0; mf < 4; ++mf)
#pragma unroll
                for (int nf = 0; nf < 4; ++nf)
                    acc[mf][nf] = __builtin_amdgcn_mfma_f32_16x16x32_bf16(
                        a[mf], b[nf], acc[mf][nf], 0, 0, 0);
        }
        __syncthreads();
    }

#pragma unroll
    for (int mf = 0; mf < 4; ++mf) {
#pragma unroll
        for (int nf = 0; nf < 4; ++nf) {
#pragma unroll
            for (int reg = 0; reg < 4; ++reg) {
                const int row = tM + wr * 64 + mf * 16 + g * 4 + reg;
                const int col = tN + wc * 64 + nf * 16 + r16;
                float v = acc[mf][nf][reg] + bias[col];
                if (MODE == 0) {
                    const int h = col / 192, j = col % 192;
                    const int b = row >> 11, t = row & 2047;
                    const size_t bh = (size_t)(b * 16 + h);
                    if (j < 64)   // Q: scale 0.125 * log2(e) -> exp2-domain softmax
                        O0[(bh * 2048 + t) * 64 + j] = (__bf16)(v * 0.18033688011112042f);
                    else if (j < 128)
                        O1[(bh * 2048 + t) * 64 + (j - 64)] = (__bf16)v;
                    else
                        O2[(bh * 64 + (j - 128)) * 2048 + t] = (__bf16)v;
                } else {
                    Of[(size_t)row * N + col] = v;
                }
            }
        }
    }
}

// ---------------------------------------------------------------------------
// Flash attention, swapped QK^T. Grid (32 qblocks, 16 heads, 2 batch),
// 256 thr (4 waves, 16 q-rows each). K/V^T tiles staged in LDS (dbuf,
// XOR-swizzled). S_T = mfma(K,Q): lane r16 = q, regs = kv -> lane-local
// softmax (2 shfls for max). O_T = mfma(V_T, P_T): q stays on r16, rescale
// is per-lane. P_T through per-wave XOR-swizzled LDS [16][64].
// ---------------------------------------------------------------------------
__global__ __launch_bounds__(256, 4)
void attn(const __bf16* __restrict__ Q, const __bf16* __restrict__ K,
          const __bf16* __restrict__ V, __bf16* __restrict__ O)
{
    __shared__ __bf16 sK[2][64 * 64];   // 8 KB each
    __shared__ __bf16 sV[2][64 * 64];   // V^T tile [d][kv]
    __shared__ __bf16 sP[64 * 64];      // 4 waves x [16 q][64 kv], swizzled

    const int tid = threadIdx.x;
    const int w   = tid >> 6, lane = tid & 63;
    const int g   = lane >> 4, r16 = lane & 15;
    const int bh  = blockIdx.z * 16 + blockIdx.y;
    const int q0  = blockIdx.x * 64 + w * 16;
    const __bf16* Qp = Q + (size_t)bh * 2048 * 64;
    const __bf16* Kp = K + (size_t)bh * 2048 * 64;
    const __bf16* Vp = V + (size_t)bh * 64 * 2048;

    const int srow_off = lane >> 3;
    const int scol     = 8 * ((lane & 7) ^ srow_off);   // pre-swizzled src col
    const int swz      = (r16 & 7) << 4;                // byte XOR for LDS reads
    char* const Pb     = (char*)sP + (w * 16 + r16) * 128;

    // Q fragments (B-operand): lane r16 = q, k = d
    bf16x8 qa[2];
#pragma unroll
    for (int kk = 0; kk < 2; ++kk)
        qa[kk] = *(const bf16x8*)(Qp + (size_t)(q0 + r16) * 64 + kk * 32 + g * 8);

    f32x4 o[4] = {};
    float mrun = -1e30f, lrun = 0.f;

    // ---- stage tile 0 ----
#pragma unroll
    for (int r = 0; r < 2; ++r) {
        const int ldsb = r * 4096 + w * 1024;
        const int row  = r * 32 + w * 8 + srow_off;
        __builtin_amdgcn_global_load_lds(AS1(Kp + (size_t)row * 64 + scol),
                                         AS3((char*)&sK[0][0] + ldsb), 16, 0, 0);
        __builtin_amdgcn_global_load_lds(AS1(Vp + (size_t)row * 2048 + scol),
                                         AS3((char*)&sV[0][0] + ldsb), 16, 0, 0);
    }
    __syncthreads();

    for (int t = 0; t < 32; ++t) {
        const int cur = t & 1;
        if (t < 31) {
            const int kvn = (t + 1) * 64;
#pragma unroll
            for (int r = 0; r < 2; ++r) {
                const int ldsb = r * 4096 + w * 1024;
                const int row  = r * 32 + w * 8 + srow_off;
                __builtin_amdgcn_global_load_lds(AS1(Kp + (size_t)(kvn + row) * 64 + scol),
                                                 AS3((char*)&sK[cur ^ 1][0] + ldsb), 16, 0, 0);
                __builtin_amdgcn_global_load_lds(AS1(Vp + (size_t)row * 2048 + kvn + scol),
                                                 AS3((char*)&sV[cur ^ 1][0] + ldsb), 16, 0, 0);
            }
        }
        // ---- S_T[kv][q] = K Q^T : A-frag = K (m=kv), B-frag = Q (n=q) ----
        bf16x8 kb[4][2];
#pragma unroll
        for (int nf = 0; nf < 4; ++nf) {
            const int row = nf * 16 + r16;
#pragma unroll
            for (int kk = 0; kk < 2; ++kk)
                kb[nf][kk] = *(const bf16x8*)((const char*)&sK[cur][0] + row * 128
                                              + ((kk * 64 + g * 16) ^ swz));
        }
        f32x4 S[4];
        __builtin_amdgcn_s_setprio(1);
#pragma unroll
        for (int nf = 0; nf < 4; ++nf) {
            f32x4 s = {};
            s = __builtin_amdgcn_mfma_f32_16x16x32_bf16(kb[nf][0], qa[0], s, 0, 0, 0);
            s = __builtin_amdgcn_mfma_f32_16x16x32_bf16(kb[nf][1], qa[1], s, 0, 0, 0);
            S[nf] = s;
        }
        __builtin_amdgcn_s_setprio(0);
        // ---- softmax (exp2 domain): lane-local 16 values + 2 shfls ----
        float rm = fmaxf(fmaxf(S[0][0], S[0][1]), fmaxf(S[0][2], S[0][3]));
#pragma unroll
        for (int nf = 1; nf < 4; ++nf)
            rm = fmaxf(rm, fmaxf(fmaxf(S[nf][0], S[nf][1]), fmaxf(S[nf][2], S[nf][3])));
        rm = fmaxf(rm, __shfl_xor(rm, 16));
        rm = fmaxf(rm, __shfl_xor(rm, 32));
        const float mn = fmaxf(mrun, rm);
        const float al = exp2f(mrun - mn);
        float ps = 0.f;
#pragma unroll
        for (int nf = 0; nf < 4; ++nf)
#pragma unroll
            for (int reg = 0; reg < 4; ++reg) {
                const float p = exp2f(S[nf][reg] - mn);
                S[nf][reg] = p;
                ps += p;
            }
        lrun = lrun * al + ps;
        mrun = mn;
#pragma unroll
        for (int df = 0; df < 4; ++df)
#pragma unroll
            for (int reg = 0; reg < 4; ++reg) o[df][reg] *= al;
        // ---- P_T -> per-wave LDS (packed 8B writes, XOR-swizzled) ----
        asm volatile("s_waitcnt lgkmcnt(0)" ::: "memory");   // WAR vs prev reads
        __builtin_amdgcn_sched_barrier(0);
#pragma unroll
        for (int nf = 0; nf < 4; ++nf) {
            bf16x4 pk = { (__bf16)S[nf][0], (__bf16)S[nf][1],
                          (__bf16)S[nf][2], (__bf16)S[nf][3] };
            *(bf16x4*)(Pb + ((nf * 32 + g * 8) ^ swz)) = pk;
        }
        asm volatile("s_waitcnt lgkmcnt(0)" ::: "memory");   // writes visible
        __builtin_amdgcn_sched_barrier(0);
        // ---- O_T += V_T P_T : A-frag = V_T (m=d), B-frag = P_T (n=q) ----
        bf16x8 pb[2];
#pragma unroll
        for (int kk = 0; kk < 2; ++kk)
            pb[kk] = *(const bf16x8*)(Pb + ((kk * 64 + g * 16) ^ swz));
        __builtin_amdgcn_s_setprio(1);
#pragma unroll
        for (int kk = 0; kk < 2; ++kk)
#pragma unroll
            for (int df = 0; df < 4; ++df) {
                const int row = df * 16 + r16;
                bf16x8 vb = *(const bf16x8*)((const char*)&sV[cur][0] + row * 128
                                             + ((kk * 64 + g * 16) ^ swz));
                o[df] = __builtin_amdgcn_mfma_f32_16x16x32_bf16(vb, pb[kk], o[df], 0, 0, 0);
            }
        __builtin_amdgcn_s_setprio(0);
        __syncthreads();   // all waves done with cur + stage of next complete
    }

    // ---- finish denominator (2 shfls) and store O_T -> Os[token][c] ----
    lrun += __shfl_xor(lrun, 16);
    lrun += __shfl_xor(lrun, 32);
    const float inv = 1.f / lrun;
    const size_t token = (size_t)blockIdx.z * 2048 + q0 + r16;
#pragma unroll
    for (int df = 0; df < 4; ++df) {
        bf16x4 ov = { (__bf16)(o[df][0] * inv), (__bf16)(o[df][1] * inv),
                      (__bf16)(o[df][2] * inv), (__bf16)(o[df][3] * inv) };
        *(bf16x4*)(O + token * 1024 + blockIdx.y * 64 + df * 16 + g * 4) = ov;
    }
}

// ---------------------------------------------------------------------------
extern "C" void kernel_launch(void* const* d_in, const int* in_sizes, int n_in,
                              void* d_out, int out_size, void* d_ws, size_t ws_size,
                              hipStream_t stream)
{
    const float* x     = (const float*)d_in[0];
    const float* Wqkv  = (const float*)d_in[1];
    const float* bqkv  = (const float*)d_in[2];
    const float* Wproj = (const float*)d_in[3];
    const float* bproj = (const float*)d_in[4];
    float* out = (float*)d_out;

    const size_t NX   = (size_t)4096 * 1024;
    const size_t NWQ  = (size_t)3072 * 1024;
    const size_t NWP  = (size_t)1024 * 1024;

    __bf16* xb  = (__bf16*)d_ws;
    __bf16* Wqb = xb  + NX;
    __bf16* Wpb = Wqb + NWQ;
    __bf16* Qs  = Wpb + NWP;           // (B,H,T,64), scaled 0.125*log2e
    __bf16* Ks  = Qs  + NX;            // (B,H,T,64)
    __bf16* Vt  = Ks  + NX;            // (B,H,64,T)
    __bf16* Os  = Vt  + NX;            // (B*T, C)

    dim3 blk(256);
    cvt_f32_bf16<<<dim3(2048), blk, 0, stream>>>(x,     xb,  (int)NX);
    cvt_f32_bf16<<<dim3(2048), blk, 0, stream>>>(Wqkv,  Wqb, (int)NWQ);
    cvt_f32_bf16<<<dim3(1024), blk, 0, stream>>>(Wproj, Wpb, (int)NWP);

    gemm_bt<0><<<dim3(24, 32), blk, 0, stream>>>(xb, Wqb, bqkv, 4096, 3072, 1024, Qs, Ks, Vt, nullptr);
    attn<<<dim3(32, 16, 2), blk, 0, stream>>>(Qs, Ks, Vt, Os);
    gemm_bt<1><<<dim3(8, 32), blk, 0, stream>>>(Os, Wpb, bproj, 4096, 1024, 1024, nullptr, nullptr, nullptr, out);
}